// Round 17
// baseline (371.251 us; speedup 1.0000x reference)
//
#include <hip/hip_runtime.h>
#include <stdint.h>

// ---- sizes ----
#define T_TOK 8192      // B*L = 4*2048
#define SEQL  2048
#define DM    1024
#define DI    2048
#define DSTATE 128
#define NH    32
#define HD    64
#define CONVD 2304      // DI + 2*DSTATE
#define DINP  4384      // 2*DI + 2*DSTATE + NH
#define LD_ZX 4480      // DINP padded to multiple of 128
#define QC    64        // chunk length
#define NCH   32        // chunks per sequence (SEQL/QC)

typedef __attribute__((ext_vector_type(8))) __bf16 bfrag;
typedef __attribute__((ext_vector_type(8))) short s16x8;
typedef __attribute__((ext_vector_type(4))) float f32x4;

__device__ __forceinline__ float bf2f(unsigned short u){
  return __uint_as_float(((unsigned)u) << 16);
}
__device__ __forceinline__ unsigned short f2bf(float f){
  unsigned u = __float_as_uint(f);
  unsigned r = (u + 0x7FFFu + ((u >> 16) & 1u)) >> 16;   // RNE
  return (unsigned short)r;
}

__device__ __forceinline__ void gl_lds16(const unsigned short* g, unsigned short* l){
  __builtin_amdgcn_global_load_lds(
      (const __attribute__((address_space(1))) void*)g,
      (__attribute__((address_space(3))) void*)l,
      16, 0, 0);
}
__device__ __forceinline__ void gl_lds4(const float* g, float* l){
  __builtin_amdgcn_global_load_lds(
      (const __attribute__((address_space(1))) void*)g,
      (__attribute__((address_space(3))) void*)l,
      4, 0, 0);
}

// ---- prep: weights f32->bf16 (3 tensors, in_proj zero-padded) + dual rmsnorm ----
// grid: [0,8576) cvt segments; [8576, 16768) rmsnorm tokens
__global__ __launch_bounds__(256) void prep_kernel(const float* __restrict__ s0,
                                                   const float* __restrict__ s1,
                                                   const float* __restrict__ s2,
                                                   unsigned short* __restrict__ d0,
                                                   unsigned short* __restrict__ d1,
                                                   unsigned short* __restrict__ d2,
                                                   const float* __restrict__ a,
                                                   const float* __restrict__ b,
                                                   const float* __restrict__ w,
                                                   unsigned short* __restrict__ out){
  int blk = blockIdx.x;
  int tid = threadIdx.x;
  if (blk < 8576){
    const float* src; unsigned short* dst; int i, srcn4;
    if (blk < 2048){
      src = s0; dst = d0; i = blk * 256 + tid; srcn4 = DM * DI / 4;
    } else if (blk < 6528){
      src = s1; dst = d1; i = (blk - 2048) * 256 + tid; srcn4 = DINP * DM / 4;
    } else {
      src = s2; dst = d2; i = (blk - 6528) * 256 + tid; srcn4 = DM * DI / 4;
    }
    ushort4 o;
    if (i < srcn4){
      float4 v = ((const float4*)src)[i];
      o.x = f2bf(v.x); o.y = f2bf(v.y); o.z = f2bf(v.z); o.w = f2bf(v.w);
    } else {
      o.x = o.y = o.z = o.w = 0;
    }
    *(ushort4*)(dst + (size_t)i * 4) = o;
    return;
  }
  // rmsnorm(h_prev) | rmsnorm(emb_next) -> combined row t
  int t = blk - 8576;
  float4 va = *(const float4*)(a + (size_t)t * DM + tid * 4);
  float4 vb = *(const float4*)(b + (size_t)t * DM + tid * 4);
  float sa = va.x*va.x + va.y*va.y + va.z*va.z + va.w*va.w;
  float sb = vb.x*vb.x + vb.y*vb.y + vb.z*vb.z + vb.w*vb.w;
  #pragma unroll
  for (int o = 32; o; o >>= 1){ sa += __shfl_down(sa, o); sb += __shfl_down(sb, o); }
  __shared__ float reda[4], redb[4];
  int wv = tid >> 6, lane = tid & 63;
  if (!lane){ reda[wv] = sa; redb[wv] = sb; }
  __syncthreads();
  float ta = reda[0] + reda[1] + reda[2] + reda[3];
  float tb = redb[0] + redb[1] + redb[2] + redb[3];
  float ra = rsqrtf(ta * (1.f/1024.f) + 1e-6f);
  float rb = rsqrtf(tb * (1.f/1024.f) + 1e-6f);
  float4 vw = *(const float4*)(w + tid * 4);
  unsigned short* o0 = out + (size_t)t * DI + tid * 4;
  o0[0] = f2bf(va.x*ra*vw.x); o0[1] = f2bf(va.y*ra*vw.y);
  o0[2] = f2bf(va.z*ra*vw.z); o0[3] = f2bf(va.w*ra*vw.w);
  unsigned short* o1 = o0 + DM;
  o1[0] = f2bf(vb.x*rb*vw.x); o1[1] = f2bf(vb.y*rb*vw.y);
  o1[2] = f2bf(vb.z*rb*vw.z); o1[3] = f2bf(vb.w*rb*vw.w);
}

// ---- bf16 GEMM (R15 structure + L2 group swizzle + optional dec fusion) ----
// 128x128 tile, BK=64, 256 thr = 4 waves. LDS swizzle u'=u^(row&7) (0 conflicts).
// Block order: XCD-bijective, then (8 M-tiles x GN N-tiles) super-tiles so the
// in-flight working set per XCD fits L2 (~4.7 MB for GN=5). M must be 8192.
// DECF: fuse dec partial dots into epilogue (out_proj only).
template<bool F32OUT, bool DECF>
__global__ __launch_bounds__(256) void gemm_bf16_kernel(const unsigned short* __restrict__ A,
                                                        const unsigned short* __restrict__ W,
                                                        void* __restrict__ Cv,
                                                        const float* __restrict__ bias,
                                                        const float* __restrict__ dw,
                                                        float* __restrict__ outd,
                                                        int M, int N, int K, int ldc, int GN){
  __shared__ unsigned short As[128 * 64];
  __shared__ unsigned short Bs[128 * 64];
  const int nN = N >> 7;
  const int xcd = blockIdx.x & 7, cc = blockIdx.x >> 3;   // grid%8==0; 64 M-tiles total
  const int gsz = 8 * GN;
  const int grp = cc / gsz, rem = cc % gsz;
  const int tm = xcd * 8 + rem / GN;
  const int tn = grp * GN + rem % GN;
  const int tid = threadIdx.x;
  const int wv = tid >> 6, lane = tid & 63;
  const int wm = wv >> 1, wn = wv & 1;
  const int rA = lane >> 3;                        // 0..7 (row within octet)
  const int cS = ((lane & 7) ^ rA) << 3;           // pre-swizzled source unit*8
  const size_t arow0 = (size_t)(tm * 128) * K;
  const size_t brow0 = (size_t)(tn * 128) * K;

  // fragment read offsets (physical unit = logical ^ (row&7)); loop-invariant
  int aoff[4][2], boff[4][2];
  #pragma unroll
  for (int f = 0; f < 4; ++f)
    #pragma unroll
    for (int kk = 0; kk < 2; ++kk){
      int ar = wm*64 + f*16 + (lane & 15);
      int br = wn*64 + f*16 + (lane & 15);
      int u  = kk*4 + (lane >> 4);
      aoff[f][kk] = ar * 64 + ((u ^ (ar & 7)) << 3);
      boff[f][kk] = br * 64 + ((u ^ (br & 7)) << 3);
    }

  f32x4 zero4 = {0.f, 0.f, 0.f, 0.f};
  f32x4 acc[4][4];
  #pragma unroll
  for (int i = 0; i < 4; ++i)
    #pragma unroll
    for (int j = 0; j < 4; ++j) acc[i][j] = zero4;

  const int nK = K >> 6;
  for (int kt = 0; kt < nK; ++kt){
    const int k0 = kt << 6;
    if (kt) __syncthreads();
    #pragma unroll
    for (int i = 0; i < 4; ++i){
      int base = (wv * 4 + i) * 8;      // 8 rows per issue; dest linear
      gl_lds16(A + arow0 + (size_t)(base + rA) * K + k0 + cS, &As[base * 64]);
      gl_lds16(W + brow0 + (size_t)(base + rA) * K + k0 + cS, &Bs[base * 64]);
    }
    __syncthreads();
    #pragma unroll
    for (int kk = 0; kk < 2; ++kk){
      bfrag af[4], bfv[4];
      #pragma unroll
      for (int f = 0; f < 4; ++f){
        af[f]  = *reinterpret_cast<const bfrag*>(&As[aoff[f][kk]]);
        bfv[f] = *reinterpret_cast<const bfrag*>(&Bs[boff[f][kk]]);
      }
      #pragma unroll
      for (int fm = 0; fm < 4; ++fm)
        #pragma unroll
        for (int fn = 0; fn < 4; ++fn)
          acc[fm][fn] = __builtin_amdgcn_mfma_f32_16x16x32_bf16(af[fm], bfv[fn], acc[fm][fn], 0, 0, 0);
    }
  }
  const int r0 = (lane >> 4) * 4, ci = lane & 15;
  // dec weights for this lane's 4 columns (DECF only)
  float dwr[3][4];
  if (DECF){
    #pragma unroll
    for (int v = 0; v < 3; ++v)
      #pragma unroll
      for (int fn = 0; fn < 4; ++fn)
        dwr[v][fn] = dw[v * DM + tn*128 + wn*64 + fn*16 + ci];
  }
  #pragma unroll
  for (int fm = 0; fm < 4; ++fm){
    #pragma unroll
    for (int r = 0; r < 4; ++r){
      const int row = tm*128 + wm*64 + fm*16 + r0 + r;
      float pd0 = 0.f, pd1 = 0.f, pd2 = 0.f;
      #pragma unroll
      for (int fn = 0; fn < 4; ++fn){
        const int col = tn*128 + wn*64 + fn*16 + ci;
        float val = acc[fm][fn][r] + (bias ? bias[col] : 0.f);
        if (F32OUT) ((float*)Cv)[(size_t)row * ldc + col] = val;
        else        ((unsigned short*)Cv)[(size_t)row * ldc + col] = f2bf(val);
        if (DECF){
          pd0 = fmaf(val, dwr[0][fn], pd0);
          pd1 = fmaf(val, dwr[1][fn], pd1);
          pd2 = fmaf(val, dwr[2][fn], pd2);
        }
      }
      if (DECF){
        #pragma unroll
        for (int m = 1; m < 16; m <<= 1){
          pd0 += __shfl_xor(pd0, m);
          pd1 += __shfl_xor(pd1, m);
          pd2 += __shfl_xor(pd2, m);
        }
        if (ci == 0){
          atomicAdd(&outd[row * 3 + 0], pd0);
          atomicAdd(&outd[row * 3 + 1], pd1);
          atomicAdd(&outd[row * 3 + 2], pd2);
        }
      }
    }
  }
}

// ---- conv(16 tok/block) + cum scan, one launch ----
// grid: [0,4608) conv (c-seg 9 x tokgroup 512); [4608, 5632) cum
__global__ __launch_bounds__(256) void convcum_kernel(const unsigned short* __restrict__ zx,
                                                      const float* __restrict__ cw,
                                                      const float* __restrict__ cb,
                                                      unsigned short* __restrict__ xbc,
                                                      const float* __restrict__ dtbias,
                                                      const float* __restrict__ alog,
                                                      float* __restrict__ cumT,
                                                      float* __restrict__ dtT,
                                                      float* __restrict__ decayG){
  int blk = blockIdx.x;
  int tid = threadIdx.x;
  if (blk < 4608){
    int c = (blk % 9) * 256 + tid;            // 0..2303
    int tg = (blk / 9) * 16;                   // token group start (16 | SEQL)
    int l0 = tg & (SEQL - 1);
    const unsigned short* base = zx + (size_t)tg * LD_ZX + DI + c;
    float v[19];
    #pragma unroll
    for (int i = 0; i < 19; ++i){
      int ll = l0 - 3 + i;
      v[i] = (ll >= 0) ? bf2f(base[(ptrdiff_t)(i - 3) * LD_ZX]) : 0.f;
    }
    float w0 = cw[c*4+0], w1 = cw[c*4+1], w2 = cw[c*4+2], w3 = cw[c*4+3];
    float cbv = cb[c];
    unsigned short* ob = xbc + (size_t)tg * CONVD + c;
    #pragma unroll
    for (int s = 0; s < 16; ++s){
      float acc = cbv + w0*v[s] + w1*v[s+1] + w2*v[s+2] + w3*v[s+3];
      float sv = acc / (1.f + expf(-acc));     // silu
      ob[(size_t)s * CONVD] = f2bf(sv);
    }
    return;
  }
  // cum: one wave per (b,h,chunk)
  int gw = (blk - 4608) * 4 + (tid >> 6);     // 0..4095
  int l = tid & 63;
  int c = gw & 31, h = (gw >> 5) & 31, b = gw >> 10;
  size_t t = (size_t)b * SEQL + c * QC + l;
  float xr = bf2f(zx[t * LD_ZX + 4352 + h]) + dtbias[h];
  float dt = (xr > 20.f) ? xr : log1pf(expf(xr));
  float A = -expf(alog[h]);
  float x = dt * A;                  // log dA
  #pragma unroll
  for (int d = 1; d < 64; d <<= 1){
    float y = __shfl_up(x, d);
    if (l >= d) x += y;
  }
  size_t o = ((size_t)(b * NH + h)) * SEQL + c * QC + l;
  cumT[o] = x;
  dtT[o] = dt;
  float tot = __shfl(x, 63);
  if (l == 0) decayG[(b * NH + h) * NCH + c] = expf(tot);
}

// ---- phase A: dS[chead][p][n] = sum_j w_j x_j[p] B_j[n]  (bf16 out) ----
__global__ __launch_bounds__(256) void chunk_dS_kernel(const unsigned short* __restrict__ xbc,
                                                       const float* __restrict__ cumT,
                                                       const float* __restrict__ dtT,
                                                       unsigned short* __restrict__ dS){
  __shared__ unsigned short Xw[64 * 64];    // [p][j] swizzled
  __shared__ unsigned short Bt[128 * 64];   // [n][j] swizzled
  __shared__ float cumS[64], dtS[64];
  const int blk = blockIdx.x;
  const int c = blk & 31, h = (blk >> 5) & 31, b = blk >> 10;
  const int tid = threadIdx.x;
  const int wv = tid >> 6, l = tid & 63;
  const size_t tokB = (size_t)b * SEQL + c * QC;
  const int bh = b * NH + h;

  if (wv == 0) gl_lds4(cumT + (size_t)bh * SEQL + c * QC + l, cumS);
  if (wv == 1) gl_lds4(dtT  + (size_t)bh * SEQL + c * QC + l, dtS);

  const int j = tid >> 2, g4 = tid & 3;
  const unsigned short* xsrc = xbc + (tokB + j) * CONVD + h * HD + g4 * 16;
  s16x8 x0 = *(const s16x8*)xsrc, x1 = *(const s16x8*)(xsrc + 8);
  const unsigned short* bsrc = xbc + (tokB + j) * CONVD + DI + g4 * 32;
  s16x8 b0 = *(const s16x8*)bsrc,        b1 = *(const s16x8*)(bsrc + 8);
  s16x8 b2 = *(const s16x8*)(bsrc + 16), b3 = *(const s16x8*)(bsrc + 24);
  __syncthreads();    // cum/dt staged

  float wj = expf(cumS[63] - cumS[j]) * dtS[j];
  const int jh = (j >> 3), jl = (j & 7);
  #pragma unroll
  for (int e = 0; e < 8; ++e){
    int p = g4 * 16 + e;
    Xw[p * 64 + ((jh ^ (p & 7)) << 3) + jl] = f2bf(bf2f((unsigned short)x0[e]) * wj);
    int p2 = p + 8;
    Xw[p2 * 64 + ((jh ^ (p2 & 7)) << 3) + jl] = f2bf(bf2f((unsigned short)x1[e]) * wj);
  }
  #pragma unroll
  for (int e = 0; e < 8; ++e){
    int n0 = g4 * 32 + e;
    Bt[(n0     ) * 64 + ((jh ^ ((n0     ) & 7)) << 3) + jl] = (unsigned short)b0[e];
    Bt[(n0 +  8) * 64 + ((jh ^ ((n0 +  8) & 7)) << 3) + jl] = (unsigned short)b1[e];
    Bt[(n0 + 16) * 64 + ((jh ^ ((n0 + 16) & 7)) << 3) + jl] = (unsigned short)b2[e];
    Bt[(n0 + 24) * 64 + ((jh ^ ((n0 + 24) & 7)) << 3) + jl] = (unsigned short)b3[e];
  }
  __syncthreads();

  f32x4 z4 = {0.f,0.f,0.f,0.f};
  f32x4 acc[4][2];
  #pragma unroll
  for (int pt = 0; pt < 4; ++pt){ acc[pt][0] = z4; acc[pt][1] = z4; }
  #pragma unroll
  for (int ks = 0; ks < 2; ++ks){
    const int au = ((ks * 4 + (l >> 4)) ^ (l & 7));
    bfrag a[4], bb[2];
    #pragma unroll
    for (int pt = 0; pt < 4; ++pt)
      a[pt] = *(const bfrag*)&Xw[(pt * 16 + (l & 15)) * 64 + au * 8];
    #pragma unroll
    for (int nt = 0; nt < 2; ++nt)
      bb[nt] = *(const bfrag*)&Bt[((wv * 2 + nt) * 16 + (l & 15)) * 64 + au * 8];
    #pragma unroll
    for (int pt = 0; pt < 4; ++pt)
      #pragma unroll
      for (int nt = 0; nt < 2; ++nt)
        acc[pt][nt] = __builtin_amdgcn_mfma_f32_16x16x32_bf16(a[pt], bb[nt], acc[pt][nt], 0, 0, 0);
  }
  unsigned short* out = dS + ((size_t)(bh * NCH + c) * 64) * 128;
  #pragma unroll
  for (int pt = 0; pt < 4; ++pt)
    #pragma unroll
    for (int nt = 0; nt < 2; ++nt)
      #pragma unroll
      for (int r = 0; r < 4; ++r){
        int p = pt * 16 + (l >> 4) * 4 + r;
        int n = (wv * 2 + nt) * 16 + (l & 15);
        out[(size_t)p * 128 + n] = f2bf(acc[pt][nt][r]);
      }
}

// ---- phase B: in-place across-chunk state scan (vectorized ushort8) ----
__global__ __launch_bounds__(256) void chunk_state_kernel(const float* __restrict__ decayG,
                                                          unsigned short* __restrict__ dS){
  int i = blockIdx.x * 256 + threadIdx.x;   // 131072 = 128 bh x 64 p x 16 n8
  int n8 = i & 15, p = (i >> 4) & 63, bh = i >> 10;
  float s[8];
  #pragma unroll
  for (int j = 0; j < 8; ++j) s[j] = 0.f;
  const float* dg = decayG + bh * NCH;
  for (int c = 0; c < NCH; ++c){
    size_t idx = ((size_t)(bh * NCH + c) * 64 + p) * 128 + n8 * 8;
    s16x8 d = *(const s16x8*)(dS + idx);
    s16x8 o;
    #pragma unroll
    for (int j = 0; j < 8; ++j) o[j] = (short)f2bf(s[j]);
    *(s16x8*)(dS + idx) = o;
    float g = dg[c];
    #pragma unroll
    for (int j = 0; j < 8; ++j) s[j] = fmaf(g, s[j], bf2f((unsigned short)d[j]));
  }
}

// ---- phase C: Y = (C B^T * G) X + e^{cum} C S^T + D x ----
__global__ __launch_bounds__(256) void chunk_Y_kernel(const unsigned short* __restrict__ xbc,
                                                      const unsigned short* __restrict__ Sb,
                                                      const float* __restrict__ cumT,
                                                      const float* __restrict__ dtT,
                                                      const float* __restrict__ Dvec,
                                                      unsigned short* __restrict__ ybuf){
  __shared__ unsigned short Cs[64 * 128];   // [tau][n] swizzled (16B units)
  __shared__ unsigned short Bs[64 * 128];   // [j][n] swizzled
  __shared__ unsigned short Xt[64 * 64];    // [p][j] swizzled
  __shared__ unsigned short Ms[64 * 64];    // [tau][j] swizzled
  __shared__ float cumS[64], dtS[64];
  const int blk = blockIdx.x;
  const int c = blk & 31, h = (blk >> 5) & 31, b = blk >> 10;
  const int tid = threadIdx.x;
  const int wv = tid >> 6, l = tid & 63;
  const size_t tokB = (size_t)b * SEQL + c * QC;
  const int bh = b * NH + h;

  #pragma unroll
  for (int kk = 0; kk < 4; ++kk){
    int k = wv * 4 + kk;
    int row = k * 4 + (l >> 4);
    int us = (l & 15) ^ (row & 7);
    gl_lds16(xbc + (tokB + row) * CONVD + 2176 + us * 8, &Cs[k * 512]);
    gl_lds16(xbc + (tokB + row) * CONVD + 2048 + us * 8, &Bs[k * 512]);
  }
  if (wv == 0) gl_lds4(cumT + (size_t)bh * SEQL + c * QC + l, cumS);
  if (wv == 1) gl_lds4(dtT  + (size_t)bh * SEQL + c * QC + l, dtS);

  {
    const int j = tid >> 2, g4 = tid & 3;
    const unsigned short* xsrc = xbc + (tokB + j) * CONVD + h * HD + g4 * 16;
    s16x8 x0 = *(const s16x8*)xsrc, x1 = *(const s16x8*)(xsrc + 8);
    const int jh = j >> 3, jl = j & 7;
    #pragma unroll
    for (int e = 0; e < 8; ++e){
      int p = g4 * 16 + e;
      Xt[p * 64 + ((jh ^ (p & 7)) << 3) + jl] = (unsigned short)x0[e];
      int p2 = p + 8;
      Xt[p2 * 64 + ((jh ^ (p2 & 7)) << 3) + jl] = (unsigned short)x1[e];
    }
  }
  __syncthreads();

  bfrag sbf[4][4];
  {
    const unsigned short* sbase = Sb + (size_t)(bh * NCH + c) * 64 * 128;
    #pragma unroll
    for (int pt = 0; pt < 4; ++pt)
      #pragma unroll
      for (int ks = 0; ks < 4; ++ks){
        int p = pt * 16 + (l & 15);
        sbf[pt][ks] = *(const bfrag*)(sbase + (size_t)p * 128 + ks * 32 + (l >> 4) * 8);
      }
  }

  f32x4 z4 = {0.f,0.f,0.f,0.f};
  f32x4 macc[4] = {z4, z4, z4, z4};
  #pragma unroll
  for (int ks = 0; ks < 4; ++ks){
    const int au = (ks * 4 + (l >> 4)) ^ (l & 7);
    bfrag ca = *(const bfrag*)&Cs[(wv * 16 + (l & 15)) * 128 + au * 8];
    #pragma unroll
    for (int jt = 0; jt < 4; ++jt){
      bfrag bb = *(const bfrag*)&Bs[(jt * 16 + (l & 15)) * 128 + au * 8];
      macc[jt] = __builtin_amdgcn_mfma_f32_16x16x32_bf16(ca, bb, macc[jt], 0, 0, 0);
    }
  }
  float cj[4], dj[4];
  #pragma unroll
  for (int jt = 0; jt < 4; ++jt){
    int jv = jt * 16 + (l & 15);
    cj[jt] = cumS[jv]; dj[jt] = dtS[jv];
  }
  float ctv[4];
  #pragma unroll
  for (int r = 0; r < 4; ++r) ctv[r] = cumS[wv * 16 + (l >> 4) * 4 + r];
  #pragma unroll
  for (int jt = 0; jt < 4; ++jt){
    int jv = jt * 16 + (l & 15);
    #pragma unroll
    for (int r = 0; r < 4; ++r){
      int tb = wv * 16 + (l >> 4) * 4 + r;
      float g = (jv <= tb) ? expf(ctv[r] - cj[jt]) * dj[jt] : 0.f;
      Ms[tb * 64 + (((jv >> 3) ^ (tb & 7)) << 3) + (jv & 7)] = f2bf(macc[jt][r] * g);
    }
  }
  f32x4 yacc[4] = {z4, z4, z4, z4};
  #pragma unroll
  for (int kj = 0; kj < 2; ++kj){
    const int au = (kj * 4 + (l >> 4)) ^ (l & 7);
    bfrag ma = *(const bfrag*)&Ms[(wv * 16 + (l & 15)) * 64 + au * 8];
    #pragma unroll
    for (int pt = 0; pt < 4; ++pt){
      bfrag wx = *(const bfrag*)&Xt[(pt * 16 + (l & 15)) * 64 + au * 8];
      yacc[pt] = __builtin_amdgcn_mfma_f32_16x16x32_bf16(ma, wx, yacc[pt], 0, 0, 0);
    }
  }
  f32x4 iacc[4] = {z4, z4, z4, z4};
  #pragma unroll
  for (int ks = 0; ks < 4; ++ks){
    const int au = (ks * 4 + (l >> 4)) ^ (l & 7);
    bfrag ca = *(const bfrag*)&Cs[(wv * 16 + (l & 15)) * 128 + au * 8];
    #pragma unroll
    for (int pt = 0; pt < 4; ++pt)
      iacc[pt] = __builtin_amdgcn_mfma_f32_16x16x32_bf16(ca, sbf[pt][ks], iacc[pt], 0, 0, 0);
  }
  const float Dh = Dvec[h];
  float er[4];
  #pragma unroll
  for (int r = 0; r < 4; ++r) er[r] = expf(ctv[r]);
  #pragma unroll
  for (int pt = 0; pt < 4; ++pt)
    #pragma unroll
    for (int r = 0; r < 4; ++r){
      int p = pt * 16 + (l & 15);
      int tb = wv * 16 + (l >> 4) * 4 + r;
      float xv = bf2f(Xt[p * 64 + (((tb >> 3) ^ (p & 7)) << 3) + (tb & 7)]);
      float yv = yacc[pt][r] + er[r] * iacc[pt][r] + Dh * xv;
      ybuf[(tokB + tb) * DI + h * HD + p] = f2bf(yv);
    }
}

// ---- gated RMSNorm (in-place) + init dec output row with bias ----
__global__ __launch_bounds__(256) void gated_kernel(const unsigned short* __restrict__ y,
                                                    const unsigned short* __restrict__ zx,
                                                    const float* __restrict__ gw,
                                                    unsigned short* __restrict__ out,
                                                    const float* __restrict__ db,
                                                    float* __restrict__ outd){
  int t = blockIdx.x, tid = threadIdx.x;
  if (tid < 3) outd[t * 3 + tid] = db[tid];   // seed dec accumulator with bias
  s16x8 yv = *(const s16x8*)(y  + (size_t)t * DI    + tid * 8);
  s16x8 zv = *(const s16x8*)(zx + (size_t)t * LD_ZX + tid * 8);
  float g[8]; float ss = 0.f;
  #pragma unroll
  for (int j = 0; j < 8; ++j){
    float yf = bf2f((unsigned short)yv[j]);
    float zf = bf2f((unsigned short)zv[j]);
    float gi = yf * (zf / (1.f + expf(-zf)));
    g[j] = gi; ss += gi * gi;
  }
  #pragma unroll
  for (int o = 32; o; o >>= 1) ss += __shfl_down(ss, o);
  __shared__ float red[4];
  int wv = tid >> 6, lane = tid & 63;
  if (!lane) red[wv] = ss;
  __syncthreads();
  float tot = red[0] + red[1] + red[2] + red[3];
  float sc = rsqrtf(tot * (1.f/2048.f) + 1e-5f);
  unsigned short* o0 = out + (size_t)t * DI + tid * 8;
  #pragma unroll
  for (int j = 0; j < 8; ++j) o0[j] = f2bf(g[j] * sc * gw[tid * 8 + j]);
}

extern "C" void kernel_launch(void* const* d_in, const int* in_sizes, int n_in,
                              void* d_out, int out_size, void* d_ws, size_t ws_size,
                              hipStream_t stream){
  const float* h_prev    = (const float*)d_in[0];
  const float* emb_next  = (const float*)d_in[1];
  const float* norm_w    = (const float*)d_in[2];
  const float* proj_W    = (const float*)d_in[3];
  const float* proj_b    = (const float*)d_in[4];
  const float* in_proj_W = (const float*)d_in[5];
  const float* conv_w    = (const float*)d_in[6];
  const float* conv_b    = (const float*)d_in[7];
  const float* dt_bias   = (const float*)d_in[8];
  const float* A_log     = (const float*)d_in[9];
  const float* Dvec      = (const float*)d_in[10];
  const float* gnorm_w   = (const float*)d_in[11];
  const float* out_proj_W= (const float*)d_in[12];
  const float* dec_W     = (const float*)d_in[13];
  const float* dec_b     = (const float*)d_in[14];

  char* ws = (char*)d_ws;
  size_t off = 0;
  auto take = [&](size_t bytes){ char* p = ws + off; off += (bytes + 255) & ~(size_t)255; return p; };
  unsigned short* wproj = (unsigned short*)take((size_t)DM * DI * 2);
  unsigned short* winp  = (unsigned short*)take((size_t)LD_ZX * DM * 2);
  unsigned short* wout  = (unsigned short*)take((size_t)DM * DI * 2);
  unsigned short* zx    = (unsigned short*)take((size_t)T_TOK * LD_ZX * 2);
  float*          cumT  = (float*)take((size_t)4 * NH * SEQL * 4);
  float*          dtT   = (float*)take((size_t)4 * NH * SEQL * 4);
  float*          decayG= (float*)take((size_t)4 * NH * NCH * 4);
  char* regionA = take((size_t)T_TOK * CONVD * 2);
  unsigned short* combined = (unsigned short*)regionA;
  unsigned short* xbc      = (unsigned short*)regionA;
  char* regionY = take((size_t)T_TOK * DI * 2);
  unsigned short* hprime = (unsigned short*)regionY;
  unsigned short* ybuf   = (unsigned short*)regionY;
  unsigned short* dS = (unsigned short*)take((size_t)128 * NCH * 64 * 128 * 2);

  float* outp = (float*)d_out;                   // [T*3] output, then [T*1024] h_k (f32)
  float* hk   = outp + (size_t)T_TOK * 3;

  // 1) prep: all weights -> bf16 + dual rmsnorm, one launch (grid 16768)
  prep_kernel<<<16768, 256, 0, stream>>>(proj_W, in_proj_W, out_proj_W,
                                         wproj, winp, wout,
                                         h_prev, emb_next, norm_w, combined);

  // 2) h_prime = combined @ proj_W^T + proj_b   (M=8192,N=1024,K=2048) grid=512, GN=8
  gemm_bf16_kernel<false,false><<<(T_TOK/128)*(DM/128), 256, 0, stream>>>(
      combined, wproj, hprime, proj_b, nullptr, nullptr, T_TOK, DM, DI, DM, 8);
  // 3) zxbcdt = h_prime @ in_proj_W^T           (M=8192,N=4480,K=1024) grid=2240, GN=5
  gemm_bf16_kernel<false,false><<<(T_TOK/128)*(LD_ZX/128), 256, 0, stream>>>(
      hprime, winp, zx, nullptr, nullptr, nullptr, T_TOK, LD_ZX, DM, LD_ZX, 5);
  // 4) conv+silu (xbc overlays dead combined) + cum scan, one launch (grid 5632)
  convcum_kernel<<<5632, 256, 0, stream>>>(zx, conv_w, conv_b, xbc,
                                           dt_bias, A_log, cumT, dtT, decayG);
  // 5) phase A: per-chunk dS
  chunk_dS_kernel<<<4096, 256, 0, stream>>>(xbc, cumT, dtT, dS);
  // 6) phase B: across-chunk state scan (in-place dS -> S_in), vectorized
  chunk_state_kernel<<<512, 256, 0, stream>>>(decayG, dS);
  // 7) phase C: Y per chunk (writes ybuf over dead hprime)
  chunk_Y_kernel<<<4096, 256, 0, stream>>>(xbc, dS, cumT, dtT, Dvec, ybuf);
  // 8) gated rmsnorm (in-place) + seed dec output with bias
  gated_kernel<<<T_TOK, 256, 0, stream>>>(ybuf, zx, gnorm_w, ybuf, dec_b, outp);
  // 9) h_k = y_gated @ out_proj_W^T -> d_out[24576..] (f32) + fused dec atomics
  gemm_bf16_kernel<true,true><<<(T_TOK/128)*(DM/128), 256, 0, stream>>>(
      ybuf, wout, hk, nullptr, dec_W, outp, T_TOK, DM, DI, DM, 8);
}

// Round 18
// 346.962 us; speedup vs baseline: 1.0700x; 1.0700x over previous
//
#include <hip/hip_runtime.h>
#include <stdint.h>

// ---- sizes ----
#define T_TOK 8192      // B*L = 4*2048
#define SEQL  2048
#define DM    1024
#define DI    2048
#define DSTATE 128
#define NH    32
#define HD    64
#define CONVD 2304      // DI + 2*DSTATE
#define DINP  4384      // 2*DI + 2*DSTATE + NH
#define LD_ZX 4480      // DINP padded to multiple of 128
#define QC    64        // chunk length
#define NCH   32        // chunks per sequence (SEQL/QC)

typedef __attribute__((ext_vector_type(8))) __bf16 bfrag;
typedef __attribute__((ext_vector_type(8))) short s16x8;
typedef __attribute__((ext_vector_type(4))) float f32x4;

__device__ __forceinline__ float bf2f(unsigned short u){
  return __uint_as_float(((unsigned)u) << 16);
}
__device__ __forceinline__ unsigned short f2bf(float f){
  unsigned u = __float_as_uint(f);
  unsigned r = (u + 0x7FFFu + ((u >> 16) & 1u)) >> 16;   // RNE
  return (unsigned short)r;
}

__device__ __forceinline__ void gl_lds16(const unsigned short* g, unsigned short* l){
  __builtin_amdgcn_global_load_lds(
      (const __attribute__((address_space(1))) void*)g,
      (__attribute__((address_space(3))) void*)l,
      16, 0, 0);
}
__device__ __forceinline__ void gl_lds4(const float* g, float* l){
  __builtin_amdgcn_global_load_lds(
      (const __attribute__((address_space(1))) void*)g,
      (__attribute__((address_space(3))) void*)l,
      4, 0, 0);
}

// ---- prep: weights f32->bf16 (3 tensors, in_proj zero-padded) + dual rmsnorm ----
// grid: [0,8576) cvt segments; [8576, 16768) rmsnorm tokens
__global__ __launch_bounds__(256) void prep_kernel(const float* __restrict__ s0,
                                                   const float* __restrict__ s1,
                                                   const float* __restrict__ s2,
                                                   unsigned short* __restrict__ d0,
                                                   unsigned short* __restrict__ d1,
                                                   unsigned short* __restrict__ d2,
                                                   const float* __restrict__ a,
                                                   const float* __restrict__ b,
                                                   const float* __restrict__ w,
                                                   unsigned short* __restrict__ out){
  int blk = blockIdx.x;
  int tid = threadIdx.x;
  if (blk < 8576){
    const float* src; unsigned short* dst; int i, srcn4;
    if (blk < 2048){
      src = s0; dst = d0; i = blk * 256 + tid; srcn4 = DM * DI / 4;
    } else if (blk < 6528){
      src = s1; dst = d1; i = (blk - 2048) * 256 + tid; srcn4 = DINP * DM / 4;
    } else {
      src = s2; dst = d2; i = (blk - 6528) * 256 + tid; srcn4 = DM * DI / 4;
    }
    ushort4 o;
    if (i < srcn4){
      float4 v = ((const float4*)src)[i];
      o.x = f2bf(v.x); o.y = f2bf(v.y); o.z = f2bf(v.z); o.w = f2bf(v.w);
    } else {
      o.x = o.y = o.z = o.w = 0;
    }
    *(ushort4*)(dst + (size_t)i * 4) = o;
    return;
  }
  // rmsnorm(h_prev) | rmsnorm(emb_next) -> combined row t
  int t = blk - 8576;
  float4 va = *(const float4*)(a + (size_t)t * DM + tid * 4);
  float4 vb = *(const float4*)(b + (size_t)t * DM + tid * 4);
  float sa = va.x*va.x + va.y*va.y + va.z*va.z + va.w*va.w;
  float sb = vb.x*vb.x + vb.y*vb.y + vb.z*vb.z + vb.w*vb.w;
  #pragma unroll
  for (int o = 32; o; o >>= 1){ sa += __shfl_down(sa, o); sb += __shfl_down(sb, o); }
  __shared__ float reda[4], redb[4];
  int wv = tid >> 6, lane = tid & 63;
  if (!lane){ reda[wv] = sa; redb[wv] = sb; }
  __syncthreads();
  float ta = reda[0] + reda[1] + reda[2] + reda[3];
  float tb = redb[0] + redb[1] + redb[2] + redb[3];
  float ra = rsqrtf(ta * (1.f/1024.f) + 1e-6f);
  float rb = rsqrtf(tb * (1.f/1024.f) + 1e-6f);
  float4 vw = *(const float4*)(w + tid * 4);
  unsigned short* o0 = out + (size_t)t * DI + tid * 4;
  o0[0] = f2bf(va.x*ra*vw.x); o0[1] = f2bf(va.y*ra*vw.y);
  o0[2] = f2bf(va.z*ra*vw.z); o0[3] = f2bf(va.w*ra*vw.w);
  unsigned short* o1 = o0 + DM;
  o1[0] = f2bf(vb.x*rb*vw.x); o1[1] = f2bf(vb.y*rb*vw.y);
  o1[2] = f2bf(vb.z*rb*vw.z); o1[3] = f2bf(vb.w*rb*vw.w);
}

// ---- bf16 GEMM (R8 structure + XCD swizzle + LDS bank-swizzle) ----
// 128x128 tile, BK=64, 256 thr = 4 waves. LDS unit u' = u ^ (row&7):
// staging keeps linear dest (rule #21) with pre-swizzled per-lane SOURCE;
// fragment reads use the swizzled physical unit. (R15: conflicts 2.75e7 -> 0)
template<bool F32OUT>
__global__ __launch_bounds__(256) void gemm_bf16_kernel(const unsigned short* __restrict__ A,
                                                        const unsigned short* __restrict__ W,
                                                        void* __restrict__ Cv,
                                                        const float* __restrict__ bias,
                                                        int M, int N, int K, int ldc){
  __shared__ unsigned short As[128 * 64];
  __shared__ unsigned short Bs[128 * 64];
  const int nN = N >> 7;
  int bid = blockIdx.x;
  const int cpx = gridDim.x >> 3;                  // grid % 8 == 0 guaranteed
  bid = (bid & 7) * cpx + (bid >> 3);              // bijective XCD swizzle
  const int tm = bid / nN, tn = bid % nN;
  const int tid = threadIdx.x;
  const int wv = tid >> 6, lane = tid & 63;
  const int wm = wv >> 1, wn = wv & 1;
  const int rA = lane >> 3;                        // 0..7 (row within octet)
  const int cS = ((lane & 7) ^ rA) << 3;           // pre-swizzled source unit*8
  const size_t arow0 = (size_t)(tm * 128) * K;
  const size_t brow0 = (size_t)(tn * 128) * K;

  // fragment read offsets (physical unit = logical ^ (row&7)); loop-invariant
  int aoff[4][2], boff[4][2];
  #pragma unroll
  for (int f = 0; f < 4; ++f)
    #pragma unroll
    for (int kk = 0; kk < 2; ++kk){
      int ar = wm*64 + f*16 + (lane & 15);
      int br = wn*64 + f*16 + (lane & 15);
      int u  = kk*4 + (lane >> 4);
      aoff[f][kk] = ar * 64 + ((u ^ (ar & 7)) << 3);
      boff[f][kk] = br * 64 + ((u ^ (br & 7)) << 3);
    }

  f32x4 zero4 = {0.f, 0.f, 0.f, 0.f};
  f32x4 acc[4][4];
  #pragma unroll
  for (int i = 0; i < 4; ++i)
    #pragma unroll
    for (int j = 0; j < 4; ++j) acc[i][j] = zero4;

  const int nK = K >> 6;
  for (int kt = 0; kt < nK; ++kt){
    const int k0 = kt << 6;
    if (kt) __syncthreads();
    #pragma unroll
    for (int i = 0; i < 4; ++i){
      int base = (wv * 4 + i) * 8;      // 8 rows per issue; dest linear
      gl_lds16(A + arow0 + (size_t)(base + rA) * K + k0 + cS, &As[base * 64]);
      gl_lds16(W + brow0 + (size_t)(base + rA) * K + k0 + cS, &Bs[base * 64]);
    }
    __syncthreads();
    #pragma unroll
    for (int kk = 0; kk < 2; ++kk){
      bfrag af[4], bfv[4];
      #pragma unroll
      for (int f = 0; f < 4; ++f){
        af[f]  = *reinterpret_cast<const bfrag*>(&As[aoff[f][kk]]);
        bfv[f] = *reinterpret_cast<const bfrag*>(&Bs[boff[f][kk]]);
      }
      #pragma unroll
      for (int fm = 0; fm < 4; ++fm)
        #pragma unroll
        for (int fn = 0; fn < 4; ++fn)
          acc[fm][fn] = __builtin_amdgcn_mfma_f32_16x16x32_bf16(af[fm], bfv[fn], acc[fm][fn], 0, 0, 0);
    }
  }
  const int r0 = (lane >> 4) * 4, ci = lane & 15;
  #pragma unroll
  for (int fm = 0; fm < 4; ++fm){
    #pragma unroll
    for (int fn = 0; fn < 4; ++fn){
      int col = tn*128 + wn*64 + fn*16 + ci;
      float bv = bias ? bias[col] : 0.f;
      #pragma unroll
      for (int r = 0; r < 4; ++r){
        int row = tm*128 + wm*64 + fm*16 + r0 + r;
        float val = acc[fm][fn][r] + bv;
        if (F32OUT) ((float*)Cv)[(size_t)row * ldc + col] = val;
        else        ((unsigned short*)Cv)[(size_t)row * ldc + col] = f2bf(val);
      }
    }
  }
}

// ---- conv(16 tok/block) + cum scan, one launch ----
// grid: [0,4608) conv (c-seg 9 x tokgroup 512); [4608, 5632) cum
__global__ __launch_bounds__(256) void convcum_kernel(const unsigned short* __restrict__ zx,
                                                      const float* __restrict__ cw,
                                                      const float* __restrict__ cb,
                                                      unsigned short* __restrict__ xbc,
                                                      const float* __restrict__ dtbias,
                                                      const float* __restrict__ alog,
                                                      float* __restrict__ cumT,
                                                      float* __restrict__ dtT,
                                                      float* __restrict__ decayG){
  int blk = blockIdx.x;
  int tid = threadIdx.x;
  if (blk < 4608){
    int c = (blk % 9) * 256 + tid;            // 0..2303
    int tg = (blk / 9) * 16;                   // token group start (16 | SEQL)
    int l0 = tg & (SEQL - 1);
    const unsigned short* base = zx + (size_t)tg * LD_ZX + DI + c;
    float v[19];
    #pragma unroll
    for (int i = 0; i < 19; ++i){
      int ll = l0 - 3 + i;
      v[i] = (ll >= 0) ? bf2f(base[(ptrdiff_t)(i - 3) * LD_ZX]) : 0.f;
    }
    float w0 = cw[c*4+0], w1 = cw[c*4+1], w2 = cw[c*4+2], w3 = cw[c*4+3];
    float cbv = cb[c];
    unsigned short* ob = xbc + (size_t)tg * CONVD + c;
    #pragma unroll
    for (int s = 0; s < 16; ++s){
      float acc = cbv + w0*v[s] + w1*v[s+1] + w2*v[s+2] + w3*v[s+3];
      float sv = acc / (1.f + expf(-acc));     // silu
      ob[(size_t)s * CONVD] = f2bf(sv);
    }
    return;
  }
  // cum: one wave per (b,h,chunk)
  int gw = (blk - 4608) * 4 + (tid >> 6);     // 0..4095
  int l = tid & 63;
  int c = gw & 31, h = (gw >> 5) & 31, b = gw >> 10;
  size_t t = (size_t)b * SEQL + c * QC + l;
  float xr = bf2f(zx[t * LD_ZX + 4352 + h]) + dtbias[h];
  float dt = (xr > 20.f) ? xr : log1pf(expf(xr));
  float A = -expf(alog[h]);
  float x = dt * A;                  // log dA
  #pragma unroll
  for (int d = 1; d < 64; d <<= 1){
    float y = __shfl_up(x, d);
    if (l >= d) x += y;
  }
  size_t o = ((size_t)(b * NH + h)) * SEQL + c * QC + l;
  cumT[o] = x;
  dtT[o] = dt;
  float tot = __shfl(x, 63);
  if (l == 0) decayG[(b * NH + h) * NCH + c] = expf(tot);
}

// ---- phase A: dS[chead][p][n] = sum_j w_j x_j[p] B_j[n]  (bf16 out) ----
__global__ __launch_bounds__(256) void chunk_dS_kernel(const unsigned short* __restrict__ xbc,
                                                       const float* __restrict__ cumT,
                                                       const float* __restrict__ dtT,
                                                       unsigned short* __restrict__ dS){
  __shared__ unsigned short Xw[64 * 64];    // [p][j] swizzled
  __shared__ unsigned short Bt[128 * 64];   // [n][j] swizzled
  __shared__ float cumS[64], dtS[64];
  const int blk = blockIdx.x;
  const int c = blk & 31, h = (blk >> 5) & 31, b = blk >> 10;
  const int tid = threadIdx.x;
  const int wv = tid >> 6, l = tid & 63;
  const size_t tokB = (size_t)b * SEQL + c * QC;
  const int bh = b * NH + h;

  if (wv == 0) gl_lds4(cumT + (size_t)bh * SEQL + c * QC + l, cumS);
  if (wv == 1) gl_lds4(dtT  + (size_t)bh * SEQL + c * QC + l, dtS);

  const int j = tid >> 2, g4 = tid & 3;
  const unsigned short* xsrc = xbc + (tokB + j) * CONVD + h * HD + g4 * 16;
  s16x8 x0 = *(const s16x8*)xsrc, x1 = *(const s16x8*)(xsrc + 8);
  const unsigned short* bsrc = xbc + (tokB + j) * CONVD + DI + g4 * 32;
  s16x8 b0 = *(const s16x8*)bsrc,        b1 = *(const s16x8*)(bsrc + 8);
  s16x8 b2 = *(const s16x8*)(bsrc + 16), b3 = *(const s16x8*)(bsrc + 24);
  __syncthreads();    // cum/dt staged

  float wj = expf(cumS[63] - cumS[j]) * dtS[j];
  const int jh = (j >> 3), jl = (j & 7);
  #pragma unroll
  for (int e = 0; e < 8; ++e){
    int p = g4 * 16 + e;
    Xw[p * 64 + ((jh ^ (p & 7)) << 3) + jl] = f2bf(bf2f((unsigned short)x0[e]) * wj);
    int p2 = p + 8;
    Xw[p2 * 64 + ((jh ^ (p2 & 7)) << 3) + jl] = f2bf(bf2f((unsigned short)x1[e]) * wj);
  }
  #pragma unroll
  for (int e = 0; e < 8; ++e){
    int n0 = g4 * 32 + e;
    Bt[(n0     ) * 64 + ((jh ^ ((n0     ) & 7)) << 3) + jl] = (unsigned short)b0[e];
    Bt[(n0 +  8) * 64 + ((jh ^ ((n0 +  8) & 7)) << 3) + jl] = (unsigned short)b1[e];
    Bt[(n0 + 16) * 64 + ((jh ^ ((n0 + 16) & 7)) << 3) + jl] = (unsigned short)b2[e];
    Bt[(n0 + 24) * 64 + ((jh ^ ((n0 + 24) & 7)) << 3) + jl] = (unsigned short)b3[e];
  }
  __syncthreads();

  f32x4 z4 = {0.f,0.f,0.f,0.f};
  f32x4 acc[4][2];
  #pragma unroll
  for (int pt = 0; pt < 4; ++pt){ acc[pt][0] = z4; acc[pt][1] = z4; }
  #pragma unroll
  for (int ks = 0; ks < 2; ++ks){
    const int au = ((ks * 4 + (l >> 4)) ^ (l & 7));
    bfrag a[4], bb[2];
    #pragma unroll
    for (int pt = 0; pt < 4; ++pt)
      a[pt] = *(const bfrag*)&Xw[(pt * 16 + (l & 15)) * 64 + au * 8];
    #pragma unroll
    for (int nt = 0; nt < 2; ++nt)
      bb[nt] = *(const bfrag*)&Bt[((wv * 2 + nt) * 16 + (l & 15)) * 64 + au * 8];
    #pragma unroll
    for (int pt = 0; pt < 4; ++pt)
      #pragma unroll
      for (int nt = 0; nt < 2; ++nt)
        acc[pt][nt] = __builtin_amdgcn_mfma_f32_16x16x32_bf16(a[pt], bb[nt], acc[pt][nt], 0, 0, 0);
  }
  unsigned short* out = dS + ((size_t)(bh * NCH + c) * 64) * 128;
  #pragma unroll
  for (int pt = 0; pt < 4; ++pt)
    #pragma unroll
    for (int nt = 0; nt < 2; ++nt)
      #pragma unroll
      for (int r = 0; r < 4; ++r){
        int p = pt * 16 + (l >> 4) * 4 + r;
        int n = (wv * 2 + nt) * 16 + (l & 15);
        out[(size_t)p * 128 + n] = f2bf(acc[pt][nt][r]);
      }
}

// ---- phase B: in-place across-chunk state scan (vectorized ushort8) ----
__global__ __launch_bounds__(256) void chunk_state_kernel(const float* __restrict__ decayG,
                                                          unsigned short* __restrict__ dS){
  int i = blockIdx.x * 256 + threadIdx.x;   // 131072 = 128 bh x 64 p x 16 n8
  int n8 = i & 15, p = (i >> 4) & 63, bh = i >> 10;
  float s[8];
  #pragma unroll
  for (int j = 0; j < 8; ++j) s[j] = 0.f;
  const float* dg = decayG + bh * NCH;
  for (int c = 0; c < NCH; ++c){
    size_t idx = ((size_t)(bh * NCH + c) * 64 + p) * 128 + n8 * 8;
    s16x8 d = *(const s16x8*)(dS + idx);
    s16x8 o;
    #pragma unroll
    for (int j = 0; j < 8; ++j) o[j] = (short)f2bf(s[j]);
    *(s16x8*)(dS + idx) = o;
    float g = dg[c];
    #pragma unroll
    for (int j = 0; j < 8; ++j) s[j] = fmaf(g, s[j], bf2f((unsigned short)d[j]));
  }
}

// ---- phase C: Y = (C B^T * G) X + e^{cum} C S^T + D x ----
__global__ __launch_bounds__(256) void chunk_Y_kernel(const unsigned short* __restrict__ xbc,
                                                      const unsigned short* __restrict__ Sb,
                                                      const float* __restrict__ cumT,
                                                      const float* __restrict__ dtT,
                                                      const float* __restrict__ Dvec,
                                                      unsigned short* __restrict__ ybuf){
  __shared__ unsigned short Cs[64 * 128];   // [tau][n] swizzled (16B units)
  __shared__ unsigned short Bs[64 * 128];   // [j][n] swizzled
  __shared__ unsigned short Xt[64 * 64];    // [p][j] swizzled
  __shared__ unsigned short Ms[64 * 64];    // [tau][j] swizzled
  __shared__ float cumS[64], dtS[64];
  const int blk = blockIdx.x;
  const int c = blk & 31, h = (blk >> 5) & 31, b = blk >> 10;
  const int tid = threadIdx.x;
  const int wv = tid >> 6, l = tid & 63;
  const size_t tokB = (size_t)b * SEQL + c * QC;
  const int bh = b * NH + h;

  #pragma unroll
  for (int kk = 0; kk < 4; ++kk){
    int k = wv * 4 + kk;
    int row = k * 4 + (l >> 4);
    int us = (l & 15) ^ (row & 7);
    gl_lds16(xbc + (tokB + row) * CONVD + 2176 + us * 8, &Cs[k * 512]);
    gl_lds16(xbc + (tokB + row) * CONVD + 2048 + us * 8, &Bs[k * 512]);
  }
  if (wv == 0) gl_lds4(cumT + (size_t)bh * SEQL + c * QC + l, cumS);
  if (wv == 1) gl_lds4(dtT  + (size_t)bh * SEQL + c * QC + l, dtS);

  {
    const int j = tid >> 2, g4 = tid & 3;
    const unsigned short* xsrc = xbc + (tokB + j) * CONVD + h * HD + g4 * 16;
    s16x8 x0 = *(const s16x8*)xsrc, x1 = *(const s16x8*)(xsrc + 8);
    const int jh = j >> 3, jl = j & 7;
    #pragma unroll
    for (int e = 0; e < 8; ++e){
      int p = g4 * 16 + e;
      Xt[p * 64 + ((jh ^ (p & 7)) << 3) + jl] = (unsigned short)x0[e];
      int p2 = p + 8;
      Xt[p2 * 64 + ((jh ^ (p2 & 7)) << 3) + jl] = (unsigned short)x1[e];
    }
  }
  __syncthreads();

  bfrag sbf[4][4];
  {
    const unsigned short* sbase = Sb + (size_t)(bh * NCH + c) * 64 * 128;
    #pragma unroll
    for (int pt = 0; pt < 4; ++pt)
      #pragma unroll
      for (int ks = 0; ks < 4; ++ks){
        int p = pt * 16 + (l & 15);
        sbf[pt][ks] = *(const bfrag*)(sbase + (size_t)p * 128 + ks * 32 + (l >> 4) * 8);
      }
  }

  f32x4 z4 = {0.f,0.f,0.f,0.f};
  f32x4 macc[4] = {z4, z4, z4, z4};
  #pragma unroll
  for (int ks = 0; ks < 4; ++ks){
    const int au = (ks * 4 + (l >> 4)) ^ (l & 7);
    bfrag ca = *(const bfrag*)&Cs[(wv * 16 + (l & 15)) * 128 + au * 8];
    #pragma unroll
    for (int jt = 0; jt < 4; ++jt){
      bfrag bb = *(const bfrag*)&Bs[(jt * 16 + (l & 15)) * 128 + au * 8];
      macc[jt] = __builtin_amdgcn_mfma_f32_16x16x32_bf16(ca, bb, macc[jt], 0, 0, 0);
    }
  }
  float cj[4], dj[4];
  #pragma unroll
  for (int jt = 0; jt < 4; ++jt){
    int jv = jt * 16 + (l & 15);
    cj[jt] = cumS[jv]; dj[jt] = dtS[jv];
  }
  float ctv[4];
  #pragma unroll
  for (int r = 0; r < 4; ++r) ctv[r] = cumS[wv * 16 + (l >> 4) * 4 + r];
  #pragma unroll
  for (int jt = 0; jt < 4; ++jt){
    int jv = jt * 16 + (l & 15);
    #pragma unroll
    for (int r = 0; r < 4; ++r){
      int tb = wv * 16 + (l >> 4) * 4 + r;
      float g = (jv <= tb) ? expf(ctv[r] - cj[jt]) * dj[jt] : 0.f;
      Ms[tb * 64 + (((jv >> 3) ^ (tb & 7)) << 3) + (jv & 7)] = f2bf(macc[jt][r] * g);
    }
  }
  f32x4 yacc[4] = {z4, z4, z4, z4};
  #pragma unroll
  for (int kj = 0; kj < 2; ++kj){
    const int au = (kj * 4 + (l >> 4)) ^ (l & 7);
    bfrag ma = *(const bfrag*)&Ms[(wv * 16 + (l & 15)) * 64 + au * 8];
    #pragma unroll
    for (int pt = 0; pt < 4; ++pt){
      bfrag wx = *(const bfrag*)&Xt[(pt * 16 + (l & 15)) * 64 + au * 8];
      yacc[pt] = __builtin_amdgcn_mfma_f32_16x16x32_bf16(ma, wx, yacc[pt], 0, 0, 0);
    }
  }
  f32x4 iacc[4] = {z4, z4, z4, z4};
  #pragma unroll
  for (int ks = 0; ks < 4; ++ks){
    const int au = (ks * 4 + (l >> 4)) ^ (l & 7);
    bfrag ca = *(const bfrag*)&Cs[(wv * 16 + (l & 15)) * 128 + au * 8];
    #pragma unroll
    for (int pt = 0; pt < 4; ++pt)
      iacc[pt] = __builtin_amdgcn_mfma_f32_16x16x32_bf16(ca, sbf[pt][ks], iacc[pt], 0, 0, 0);
  }
  const float Dh = Dvec[h];
  float er[4];
  #pragma unroll
  for (int r = 0; r < 4; ++r) er[r] = expf(ctv[r]);
  #pragma unroll
  for (int pt = 0; pt < 4; ++pt)
    #pragma unroll
    for (int r = 0; r < 4; ++r){
      int p = pt * 16 + (l & 15);
      int tb = wv * 16 + (l >> 4) * 4 + r;
      float xv = bf2f(Xt[p * 64 + (((tb >> 3) ^ (p & 7)) << 3) + (tb & 7)]);
      float yv = yacc[pt][r] + er[r] * iacc[pt][r] + Dh * xv;
      ybuf[(tokB + tb) * DI + h * HD + p] = f2bf(yv);
    }
}

// ---- gated RMSNorm: out = gw * normalize(y * silu(z)); safe in-place on y ----
__global__ __launch_bounds__(256) void gated_kernel(const unsigned short* __restrict__ y,
                                                    const unsigned short* __restrict__ zx,
                                                    const float* __restrict__ gw,
                                                    unsigned short* __restrict__ out){
  int t = blockIdx.x, tid = threadIdx.x;
  s16x8 yv = *(const s16x8*)(y  + (size_t)t * DI    + tid * 8);
  s16x8 zv = *(const s16x8*)(zx + (size_t)t * LD_ZX + tid * 8);
  float g[8]; float ss = 0.f;
  #pragma unroll
  for (int j = 0; j < 8; ++j){
    float yf = bf2f((unsigned short)yv[j]);
    float zf = bf2f((unsigned short)zv[j]);
    float gi = yf * (zf / (1.f + expf(-zf)));
    g[j] = gi; ss += gi * gi;
  }
  #pragma unroll
  for (int o = 32; o; o >>= 1) ss += __shfl_down(ss, o);
  __shared__ float red[4];
  int wv = tid >> 6, lane = tid & 63;
  if (!lane) red[wv] = ss;
  __syncthreads();
  float tot = red[0] + red[1] + red[2] + red[3];
  float sc = rsqrtf(tot * (1.f/2048.f) + 1e-5f);
  unsigned short* o0 = out + (size_t)t * DI + tid * 8;
  #pragma unroll
  for (int j = 0; j < 8; ++j) o0[j] = f2bf(g[j] * sc * gw[tid * 8 + j]);
}

// ---- dec: one wave per token; computes all 3 outputs, reads h_k once ----
__global__ __launch_bounds__(256) void dec_kernel(const float* __restrict__ hk,
                                                  const float* __restrict__ dw,
                                                  const float* __restrict__ db,
                                                  float* __restrict__ out){
  int t = (blockIdx.x * 256 + threadIdx.x) >> 6;    // 0..8191
  int lane = threadIdx.x & 63;
  const float* hr = hk + (size_t)t * DM + lane * 16;
  float h[16];
  #pragma unroll
  for (int j = 0; j < 16; ++j) h[j] = hr[j];
  float a0 = 0.f, a1 = 0.f, a2 = 0.f;
  const float* w0 = dw + lane * 16;
  const float* w1 = dw + DM + lane * 16;
  const float* w2 = dw + 2 * DM + lane * 16;
  #pragma unroll
  for (int j = 0; j < 16; ++j){
    a0 = fmaf(h[j], w0[j], a0);
    a1 = fmaf(h[j], w1[j], a1);
    a2 = fmaf(h[j], w2[j], a2);
  }
  #pragma unroll
  for (int o = 32; o; o >>= 1){
    a0 += __shfl_down(a0, o);
    a1 += __shfl_down(a1, o);
    a2 += __shfl_down(a2, o);
  }
  if (!lane){
    out[t * 3 + 0] = a0 + db[0];
    out[t * 3 + 1] = a1 + db[1];
    out[t * 3 + 2] = a2 + db[2];
  }
}

extern "C" void kernel_launch(void* const* d_in, const int* in_sizes, int n_in,
                              void* d_out, int out_size, void* d_ws, size_t ws_size,
                              hipStream_t stream){
  const float* h_prev    = (const float*)d_in[0];
  const float* emb_next  = (const float*)d_in[1];
  const float* norm_w    = (const float*)d_in[2];
  const float* proj_W    = (const float*)d_in[3];
  const float* proj_b    = (const float*)d_in[4];
  const float* in_proj_W = (const float*)d_in[5];
  const float* conv_w    = (const float*)d_in[6];
  const float* conv_b    = (const float*)d_in[7];
  const float* dt_bias   = (const float*)d_in[8];
  const float* A_log     = (const float*)d_in[9];
  const float* Dvec      = (const float*)d_in[10];
  const float* gnorm_w   = (const float*)d_in[11];
  const float* out_proj_W= (const float*)d_in[12];
  const float* dec_W     = (const float*)d_in[13];
  const float* dec_b     = (const float*)d_in[14];

  char* ws = (char*)d_ws;
  size_t off = 0;
  auto take = [&](size_t bytes){ char* p = ws + off; off += (bytes + 255) & ~(size_t)255; return p; };
  unsigned short* wproj = (unsigned short*)take((size_t)DM * DI * 2);
  unsigned short* winp  = (unsigned short*)take((size_t)LD_ZX * DM * 2);
  unsigned short* wout  = (unsigned short*)take((size_t)DM * DI * 2);
  unsigned short* zx    = (unsigned short*)take((size_t)T_TOK * LD_ZX * 2);
  float*          cumT  = (float*)take((size_t)4 * NH * SEQL * 4);
  float*          dtT   = (float*)take((size_t)4 * NH * SEQL * 4);
  float*          decayG= (float*)take((size_t)4 * NH * NCH * 4);
  char* regionA = take((size_t)T_TOK * CONVD * 2);
  unsigned short* combined = (unsigned short*)regionA;
  unsigned short* xbc      = (unsigned short*)regionA;
  char* regionY = take((size_t)T_TOK * DI * 2);
  unsigned short* hprime = (unsigned short*)regionY;
  unsigned short* ybuf   = (unsigned short*)regionY;
  unsigned short* dS = (unsigned short*)take((size_t)128 * NCH * 64 * 128 * 2);

  float* outp = (float*)d_out;                   // [T*3] output, then [T*1024] h_k (f32)
  float* hk   = outp + (size_t)T_TOK * 3;

  // 1) prep: all weights -> bf16 + dual rmsnorm, one launch (grid 16768)
  prep_kernel<<<16768, 256, 0, stream>>>(proj_W, in_proj_W, out_proj_W,
                                         wproj, winp, wout,
                                         h_prev, emb_next, norm_w, combined);

  // 2) h_prime = combined @ proj_W^T + proj_b   (M=8192,N=1024,K=2048) grid=512
  gemm_bf16_kernel<false><<<(T_TOK/128)*(DM/128), 256, 0, stream>>>(combined, wproj, hprime, proj_b,
                                                                    T_TOK, DM, DI, DM);
  // 3) zxbcdt = h_prime @ in_proj_W^T           (M=8192,N=4480,K=1024) grid=2240
  gemm_bf16_kernel<false><<<(T_TOK/128)*(LD_ZX/128), 256, 0, stream>>>(hprime, winp, zx, nullptr,
                                                                       T_TOK, LD_ZX, DM, LD_ZX);
  // 4) conv+silu (xbc overlays dead combined) + cum scan, one launch (grid 5632)
  convcum_kernel<<<5632, 256, 0, stream>>>(zx, conv_w, conv_b, xbc,
                                           dt_bias, A_log, cumT, dtT, decayG);
  // 5) phase A: per-chunk dS
  chunk_dS_kernel<<<4096, 256, 0, stream>>>(xbc, cumT, dtT, dS);
  // 6) phase B: across-chunk state scan (in-place dS -> S_in), vectorized
  chunk_state_kernel<<<512, 256, 0, stream>>>(decayG, dS);
  // 7) phase C: Y per chunk (writes ybuf over dead hprime)
  chunk_Y_kernel<<<4096, 256, 0, stream>>>(xbc, dS, cumT, dtT, Dvec, ybuf);
  // 8) gated rmsnorm, in-place on ybuf
  gated_kernel<<<T_TOK, 256, 0, stream>>>(ybuf, zx, gnorm_w, ybuf);
  // 9) h_k = y_gated @ out_proj_W^T -> d_out[24576..] as f32 (grid=512)
  gemm_bf16_kernel<true><<<(T_TOK/128)*(DM/128), 256, 0, stream>>>(ybuf, wout, hk, nullptr,
                                                                   T_TOK, DM, DI, DM);
  // 10) output = h_k @ dec_W^T + dec_b -> d_out[0..24576) as f32
  dec_kernel<<<T_TOK/4, 256, 0, stream>>>(hk, dec_W, dec_b, outp);
}